// Round 1
// baseline (178.222 us; speedup 1.0000x reference)
//
#include <hip/hip_runtime.h>

// CG tensor product, restructured round: one block per (triple, i).
// Output = 99*C2 fp32 (~104 MB) -> pure write-BW problem (compute ~150M FMA ~ 2us).
// Old kernel: 23 barrier-separated micro-phases/block, 1-7KB store bursts,
// 1024 blocks -> ~2.6 TB/s effective writes. New: 11776 blocks, ONE barrier
// pair each, one contiguous 2-14KB coalesced float4 burst per block.

#define C2 (512 * 512)

struct Ptrs {
    const float* x[4];
    const float* cg[23];
};

// F(t, l1, l2, L, out_base_in_C2_units)
#define TRIPLE_LIST(F) \
    F(0, 0, 0, 0, 0) \
    F(1, 0, 1, 1, 4) \
    F(2, 0, 2, 2, 22) \
    F(3, 0, 3, 3, 57) \
    F(4, 1, 1, 0, 1) \
    F(5, 1, 1, 1, 7) \
    F(6, 1, 1, 2, 27) \
    F(7, 1, 2, 1, 10) \
    F(8, 1, 2, 2, 32) \
    F(9, 1, 2, 3, 64) \
    F(10, 1, 3, 2, 37) \
    F(11, 1, 3, 3, 71) \
    F(12, 2, 2, 0, 2) \
    F(13, 2, 2, 1, 13) \
    F(14, 2, 2, 2, 42) \
    F(15, 2, 2, 3, 78) \
    F(16, 2, 3, 1, 16) \
    F(17, 2, 3, 2, 47) \
    F(18, 2, 3, 3, 85) \
    F(19, 3, 3, 0, 3) \
    F(20, 3, 3, 1, 19) \
    F(21, 3, 3, 2, 52) \
    F(22, 3, 3, 3, 92)

template <int T, int L1, int L2, int LL, int OB>
__device__ __forceinline__ void triple_block(
        const Ptrs& p, float* __restrict__ out, int i, int tid,
        float* __restrict__ xT, float* __restrict__ ys, float* __restrict__ stg) {
    constexpr int NI = 2 * L1 + 1;
    constexpr int NJ = 2 * L2 + 1;
    constexpr int NW = 2 * LL + 1;

    // ---- stage the FULL x_{l2} matrix (512 x NJ, contiguous) into LDS ----
    // 512*NJ floats = 128*NJ float4s; coalesced; source is L2/L3-resident (32KB total x).
    {
        const float4* src4 = (const float4*)p.x[L2];
        float4* dst4 = (float4*)xT;
        #pragma unroll
        for (int k = tid; k < 128 * NJ; k += 256) dst4[k] = src4[k];
    }

    // ---- y slice for this (triple, i): ys[n*NW + M] = sum_m cg[M][n][m] * xi[m] ----
    if (tid < NJ * NW) {
        const int n = tid / NW;
        const int M = tid % NW;
        const float* cg = p.cg[T] + (M * NJ + n) * NI;
        const float* xi = p.x[L1] + i * NI;
        float s = 0.f;
        #pragma unroll
        for (int m = 0; m < NI; ++m) s = fmaf(cg[m], xi[m], s);
        ys[tid] = s;
    }
    __syncthreads();

    // ---- each thread computes 2 full j-rows (j = tid, tid+256) into staging ----
    // xT reads: lane stride NJ (odd) -> <=2 lanes/bank, conflict-free.
    // ys reads: uniform address -> broadcast, free.
    float xj0[NJ], xj1[NJ];
    #pragma unroll
    for (int n = 0; n < NJ; ++n) {
        xj0[n] = xT[tid * NJ + n];
        xj1[n] = xT[(tid + 256) * NJ + n];
    }
    #pragma unroll
    for (int M = 0; M < NW; ++M) {
        float a0 = 0.f, a1 = 0.f;
        #pragma unroll
        for (int n = 0; n < NJ; ++n) {
            const float yv = ys[n * NW + M];
            a0 = fmaf(xj0[n], yv, a0);
            a1 = fmaf(xj1[n], yv, a1);
        }
        // stride NW (odd) across lanes -> conflict-free
        stg[tid * NW + M] = a0;
        stg[(tid + 256) * NW + M] = a1;
    }
    __syncthreads();

    // ---- ONE contiguous coalesced burst: 512*NW floats = 128*NW float4 ----
    // dst 16B-aligned: OB*C2*4 is 1MB-mult, i*512*NW*4 is 2KB-mult.
    const float4* s4 = (const float4*)stg;
    float4* dst = (float4*)(out + (size_t)OB * C2 + (size_t)i * (512 * NW));
    #pragma unroll
    for (int k = tid; k < 128 * NW; k += 256) dst[k] = s4[k];
}

__global__ __launch_bounds__(256) void cg_tp_kernel(Ptrs p, float* __restrict__ out) {
    // 28.9 KB LDS -> 5 blocks/CU; VGPR small -> LDS-limited occupancy 20 waves/CU.
    __shared__ float xT[512 * 7];
    __shared__ float ys[7 * 7];
    __shared__ float stg[512 * 7];
    const int tid = threadIdx.x;
    const int t = blockIdx.x >> 9;   // triple index, uniform per block
    const int i = blockIdx.x & 511;  // i-row, fast-varying -> consecutive blocks
                                     // write consecutive 2-14KB output spans
    switch (t) {
#define TCASE(T, L1, L2, LL, OB) \
        case T: triple_block<T, L1, L2, LL, OB>(p, out, i, tid, xT, ys, stg); break;
        TRIPLE_LIST(TCASE)
#undef TCASE
    }
}

extern "C" void kernel_launch(void* const* d_in, const int* in_sizes, int n_in,
                              void* d_out, int out_size, void* d_ws, size_t ws_size,
                              hipStream_t stream) {
    Ptrs p;
    for (int l = 0; l < 4; ++l) p.x[l] = (const float*)d_in[l];
    for (int t = 0; t < 23; ++t) p.cg[t] = (const float*)d_in[4 + t];
    cg_tp_kernel<<<dim3(23 * 512), dim3(256), 0, stream>>>(p, (float*)d_out);
}

// Round 3
// 173.857 us; speedup vs baseline: 1.0251x; 1.0251x over previous
//
#include <hip/hip_runtime.h>

// CG tensor product — zero-__syncthreads wave-streaming, with explicit
// wave-local LDS fences (round-2 post-mortem: barrier-free LDS RAW through
// float-write/float4-read was reordered -> stale staging data; fix is
// s_waitcnt lgkmcnt(0) + compiler memory clobber at RAW and WAR points).
//
// Output = 99*C2 fp32 (~99 MiB) -> pure write-BW problem. Inputs (x: 32KB,
// cg: few KB) are L1-resident -> no input staging. y (<=49 wave-uniform vals)
// is broadcast via __shfl, no LDS. Only LDS use: wave-private transpose of
// per-row NW-float results into one contiguous 1-7KB float4 store burst per
// item. 5 blocks/CU (LDS-bound), 20 waves/CU of independent store streams.

#define C2 (512 * 512)
#define NBLOCKS 1472
#define NWAVES (NBLOCKS * 4)     // 5888
#define NITEMS (23 * 512 * 2)    // 23552 = (t, i, j-half); exactly 4 per wave

struct Ptrs {
    const float* x[4];
    const float* cg[23];
};

// F(t, l1, l2, L, out_base_in_C2_float_units)
#define TRIPLE_LIST(F) \
    F(0, 0, 0, 0, 0) \
    F(1, 0, 1, 1, 4) \
    F(2, 0, 2, 2, 22) \
    F(3, 0, 3, 3, 57) \
    F(4, 1, 1, 0, 1) \
    F(5, 1, 1, 1, 7) \
    F(6, 1, 1, 2, 27) \
    F(7, 1, 2, 1, 10) \
    F(8, 1, 2, 2, 32) \
    F(9, 1, 2, 3, 64) \
    F(10, 1, 3, 2, 37) \
    F(11, 1, 3, 3, 71) \
    F(12, 2, 2, 0, 2) \
    F(13, 2, 2, 1, 13) \
    F(14, 2, 2, 2, 42) \
    F(15, 2, 2, 3, 78) \
    F(16, 2, 3, 1, 16) \
    F(17, 2, 3, 2, 47) \
    F(18, 2, 3, 3, 85) \
    F(19, 3, 3, 0, 3) \
    F(20, 3, 3, 1, 19) \
    F(21, 3, 3, 2, 52) \
    F(22, 3, 3, 3, 92)

// Wave-local LDS ordering edge: all outstanding DS ops complete, and the
// compiler may not move memory ops across it (nor reschedule around it).
__device__ __forceinline__ void lds_fence() {
    asm volatile("s_waitcnt lgkmcnt(0)" ::: "memory");
    __builtin_amdgcn_sched_barrier(0);
}

template <int T, int L1, int L2, int LL, int OB>
__device__ __forceinline__ void do_item(const Ptrs& p, float* __restrict__ out,
                                        int i, int jh, int lane, float* stg) {
    constexpr int NI = 2 * L1 + 1;
    constexpr int NJ = 2 * L2 + 1;
    constexpr int NW = 2 * LL + 1;
    constexpr int NY = NJ * NW;   // <= 49

    // ---- y[n*NW+M] = sum_m cg[M][n][m]*xi[m]: one element per lane
    //      (clamped index, unconditional -> defined in all source lanes),
    //      then wave-uniform register broadcast via __shfl. No LDS. ----
    float yr[NY];
    {
        const int lidx = (lane < NY) ? lane : 0;
        const int n = lidx / NW;
        const int M = lidx % NW;
        const float* cg = p.cg[T] + (M * NJ + n) * NI;
        const float* xi = p.x[L1] + i * NI;   // L1-resident
        float s = 0.f;
        #pragma unroll
        for (int m = 0; m < NI; ++m) s = fmaf(cg[m], xi[m], s);
        #pragma unroll
        for (int q = 0; q < NY; ++q) yr[q] = __shfl(s, q);
    }

    const float* xq = p.x[L2] + (jh * 256) * NJ;   // L1-resident
    float* ob = out + (size_t)OB * C2 + (size_t)i * (512 * NW) + jh * (256 * NW);

    // ---- 256 rows: compute -> wave-private LDS (lane stride NW, odd ->
    //      conflict-free), then ONE contiguous coalesced float4 burst. ----
    #pragma unroll
    for (int r4 = 0; r4 < 4; ++r4) {
        const int row = r4 * 64 + lane;
        const float* xrow = xq + row * NJ;
        float xj[NJ];
        #pragma unroll
        for (int n = 0; n < NJ; ++n) xj[n] = xrow[n];

        float acc[NW] = {};
        #pragma unroll
        for (int n = 0; n < NJ; ++n) {
            #pragma unroll
            for (int M = 0; M < NW; ++M)
                acc[M] = fmaf(yr[n * NW + M], xj[n], acc[M]);
        }
        #pragma unroll
        for (int M = 0; M < NW; ++M) stg[row * NW + M] = acc[M];
    }

    lds_fence();   // RAW: staging writes complete before float4 read-back

    {
        const float4* s4 = (const float4*)stg;     // contiguous b128: conflict-free
        float4* d4 = (float4*)ob;                  // 16B-aligned (all terms mult of 4 floats)
        #pragma unroll
        for (int k = lane; k < 64 * NW; k += 64) d4[k] = s4[k];
    }

    lds_fence();   // WAR: read-back complete before next item's staging writes
}

__global__ __launch_bounds__(256) void cg_tp_kernel(Ptrs p, float* __restrict__ out) {
    // wave-private staging: 4 waves * 256*7 floats = 28672 B -> 5 blocks/CU
    __shared__ float stg_s[4][256 * 7];
    const int wid = threadIdx.x >> 6;
    const int lane = threadIdx.x & 63;
    float* stg = stg_s[wid];

    // item = t*1024 + i*2 + jh; stride NWAVES mixes triples across waves
    for (int item = blockIdx.x * 4 + wid; item < NITEMS; item += NWAVES) {
        const int t = item >> 10;
        const int i = (item >> 1) & 511;
        const int jh = item & 1;
        switch (t) {
#define TC(T, L1, L2, LL, OB) \
            case T: do_item<T, L1, L2, LL, OB>(p, out, i, jh, lane, stg); break;
            TRIPLE_LIST(TC)
#undef TC
        }
    }
}

extern "C" void kernel_launch(void* const* d_in, const int* in_sizes, int n_in,
                              void* d_out, int out_size, void* d_ws, size_t ws_size,
                              hipStream_t stream) {
    Ptrs p;
    for (int l = 0; l < 4; ++l) p.x[l] = (const float*)d_in[l];
    for (int t = 0; t < 23; ++t) p.cg[t] = (const float*)d_in[4 + t];
    cg_tp_kernel<<<dim3(NBLOCKS), dim3(256), 0, stream>>>(p, (float*)d_out);
}